// Round 2
// baseline (4211.358 us; speedup 1.0000x reference)
//
#include <hip/hip_runtime.h>
#include <math.h>

// Problem constants (from reference): M=131072 rows, N=4000 verts, D=16.
#define M_ROWS 131072
#define N_VERTS 4000
#define D_DIM 16

// fp32-screening tie margin. Worst-case fp32 dot error is ~1e-4 absolute
// (16 terms, |terms| sum ~O(10-100)); 1e-2 is ~100x safety. Rows whose
// top-2 gap is below this get an exact fp64 rescan (~0.3% of rows).
#define TIE_EPS 1e-2f

// ---------------------------------------------------------------------------
// Kernel 1: y_sq[n] = sum_d verts[n][d]^2   (N=4000, trivial)
// ---------------------------------------------------------------------------
__global__ void ysq_kernel(const float* __restrict__ verts,
                           float* __restrict__ ysq) {
    int n = blockIdx.x * blockDim.x + threadIdx.x;
    if (n < N_VERTS) {
        const float* y = verts + n * D_DIM;
        float a = 0.f;
#pragma unroll
        for (int d = 0; d < D_DIM; ++d) a = fmaf(y[d], y[d], a);
        ysq[n] = a;
    }
}

// ---------------------------------------------------------------------------
// Kernel 2: per-row argmin over N verts of (y_sq - 2*dot(x,y)), then gather
// colors. One thread = one row; y addresses are wave-uniform -> s_load.
// Tracks best AND second-best; ambiguous rows (gap <= TIE_EPS) rescan in
// fp64, which reproduces the float64 numpy reference argmin exactly
// (strict < keeps the first index on ties, matching jnp/np.argmin).
// ---------------------------------------------------------------------------
__global__ __launch_bounds__(256, 2) void nn_kernel(
    const float* __restrict__ x_all,    // (M,16)
    const float* __restrict__ colors,   // (N,3)
    const float* __restrict__ verts,    // (N,16)
    const float* __restrict__ ysq,      // (N,)
    float* __restrict__ out)            // (M,3)
{
    const int m = blockIdx.x * blockDim.x + threadIdx.x;

    const float4* xv = (const float4*)(x_all + (size_t)m * D_DIM);
    const float4 x0 = xv[0], x1 = xv[1], x2 = xv[2], x3 = xv[3];

    float best = INFINITY;
    float second = INFINITY;
    int bestIdx = 0;

#pragma unroll 2
    for (int n = 0; n < N_VERTS; ++n) {
        const float* y = verts + n * D_DIM;   // wave-uniform address
        float c0 = x0.x * y[0];
        float c1 = x0.y * y[1];
        float c2 = x0.z * y[2];
        float c3 = x0.w * y[3];
        c0 = fmaf(x1.x, y[4], c0);
        c1 = fmaf(x1.y, y[5], c1);
        c2 = fmaf(x1.z, y[6], c2);
        c3 = fmaf(x1.w, y[7], c3);
        c0 = fmaf(x2.x, y[8], c0);
        c1 = fmaf(x2.y, y[9], c1);
        c2 = fmaf(x2.z, y[10], c2);
        c3 = fmaf(x2.w, y[11], c3);
        c0 = fmaf(x3.x, y[12], c0);
        c1 = fmaf(x3.y, y[13], c1);
        c2 = fmaf(x3.z, y[14], c2);
        c3 = fmaf(x3.w, y[15], c3);
        const float dot = (c0 + c1) + (c2 + c3);
        const float s = fmaf(-2.0f, dot, ysq[n]);
        // best/second-best tracking (strict < -> first index wins ties)
        if (s < best) {
            second = best;
            best = s;
            bestIdx = n;
        } else if (s < second) {
            second = s;
        }
    }

    // Ambiguous: fp32 rounding could have flipped the winner. Redo in fp64.
    if (second - best <= TIE_EPS) {
        double bx[D_DIM];
#pragma unroll
        for (int d = 0; d < D_DIM; ++d)
            bx[d] = (double)x_all[(size_t)m * D_DIM + d];
        double dbest = INFINITY;
        int dIdx = 0;
        for (int n = 0; n < N_VERTS; ++n) {
            const float* y = verts + n * D_DIM;
            double dot = 0.0, ys = 0.0;
#pragma unroll
            for (int d = 0; d < D_DIM; ++d) {
                const double yd = (double)y[d];
                dot = fma(bx[d], yd, dot);
                ys = fma(yd, yd, ys);
            }
            const double s = ys - 2.0 * dot;
            if (s < dbest) { dbest = s; dIdx = n; }
        }
        bestIdx = dIdx;
    }

    const float* c = colors + (size_t)bestIdx * 3;
    float* o = out + (size_t)m * 3;
    o[0] = c[0];
    o[1] = c[1];
    o[2] = c[2];
}

// ---------------------------------------------------------------------------
extern "C" void kernel_launch(void* const* d_in, const int* in_sizes, int n_in,
                              void* d_out, int out_size, void* d_ws, size_t ws_size,
                              hipStream_t stream) {
    const float* cse_embedding       = (const float*)d_in[0]; // (M,16)
    const float* verts_colors        = (const float*)d_in[1]; // (N,3)
    const float* verts_cse_embedding = (const float*)d_in[2]; // (N,16)
    float* out = (float*)d_out;                               // (M,3)
    float* ysq = (float*)d_ws;                                // N floats scratch

    ysq_kernel<<<(N_VERTS + 255) / 256, 256, 0, stream>>>(verts_cse_embedding, ysq);

    nn_kernel<<<M_ROWS / 256, 256, 0, stream>>>(
        cse_embedding, verts_colors, verts_cse_embedding, ysq, out);
}

// Round 3
// 1035.257 us; speedup vs baseline: 4.0679x; 4.0679x over previous
//
#include <hip/hip_runtime.h>
#include <math.h>

// Problem constants (from reference): M=131072 rows, N=4000 verts, D=16.
#define M_ROWS   131072
#define N_VERTS  4000
#define D_DIM    16
#define CHUNK    1000          // N_VERTS / 4 waves per block

// fp32-screening tie margin. Worst-case fp32 score error ~1e-4; 1e-2 is
// ~50-100x safety. Rows whose top-2 gap <= this get an exact fp64 rescan
// (expected ~500 of 131072 rows).
#define TIE_EPS 1e-2f

// d_ws layout (bytes):
//   [0      .. 16000)  ysq: N_VERTS floats
//   [16000  .. 16004)  cnt: int (ambiguous-row counter)
//   [16384  .. ...  )  list: ambiguous row indices (int)
#define WS_YSQ_OFF   0
#define WS_CNT_OFF   16000
#define WS_LIST_OFF  16384

// ---------------------------------------------------------------------------
// Kernel 1: y_sq[n] = sum_d verts[n][d]^2 ; thread 0 also zeroes the counter
// (d_ws is re-poisoned to 0xAA before every call).
// ---------------------------------------------------------------------------
__global__ void ysq_kernel(const float* __restrict__ verts,
                           float* __restrict__ ysq,
                           int* __restrict__ cnt) {
    int n = blockIdx.x * blockDim.x + threadIdx.x;
    if (n == 0) *cnt = 0;
    if (n < N_VERTS) {
        const float* y = verts + n * D_DIM;
        float a = 0.f;
#pragma unroll
        for (int d = 0; d < D_DIM; ++d) a = fmaf(y[d], y[d], a);
        ysq[n] = a;
    }
}

// ---------------------------------------------------------------------------
// Kernel 2 (screen): block = 64 rows x 4 vert-chunks. Lane l of wave w scans
// rows m = blockIdx*64 + l over verts [w*1000, (w+1)*1000). n is wave-uniform
// -> y loads scalarize to s_load (verified R2: VGPR=32/SGPR=64). 32 waves/CU.
// LDS merge of the 4 per-chunk (best, second, idx) triples; ambiguous rows
// are compacted into a list for the fp64 rescan kernel.
// ---------------------------------------------------------------------------
__global__ __launch_bounds__(256, 8) void screen_kernel(
    const float* __restrict__ x_all,    // (M,16)
    const float* __restrict__ colors,   // (N,3)
    const float* __restrict__ verts,    // (N,16)
    const float* __restrict__ ysq,      // (N,)
    float* __restrict__ out,            // (M,3)
    int* __restrict__ cnt,
    int* __restrict__ list,
    int list_cap)
{
    __shared__ float s_best[4][64];
    __shared__ float s_second[4][64];
    __shared__ int   s_idx[4][64];

    const int wave = threadIdx.x >> 6;
    const int lane = threadIdx.x & 63;
    const int m = blockIdx.x * 64 + lane;

    const float4* xv = (const float4*)(x_all + (size_t)m * D_DIM);
    const float4 x0 = xv[0], x1 = xv[1], x2 = xv[2], x3 = xv[3];

    float best = INFINITY, second = INFINITY;
    int bestIdx = 0;

    const int n0 = wave * CHUNK;
    const int n1 = n0 + CHUNK;
#pragma unroll 2
    for (int n = n0; n < n1; ++n) {
        const float* y = verts + n * D_DIM;   // wave-uniform -> s_load
        float c0 = x0.x * y[0];
        float c1 = x0.y * y[1];
        float c2 = x0.z * y[2];
        float c3 = x0.w * y[3];
        c0 = fmaf(x1.x, y[4],  c0);
        c1 = fmaf(x1.y, y[5],  c1);
        c2 = fmaf(x1.z, y[6],  c2);
        c3 = fmaf(x1.w, y[7],  c3);
        c0 = fmaf(x2.x, y[8],  c0);
        c1 = fmaf(x2.y, y[9],  c1);
        c2 = fmaf(x2.z, y[10], c2);
        c3 = fmaf(x2.w, y[11], c3);
        c0 = fmaf(x3.x, y[12], c0);
        c1 = fmaf(x3.y, y[13], c1);
        c2 = fmaf(x3.z, y[14], c2);
        c3 = fmaf(x3.w, y[15], c3);
        const float dot = (c0 + c1) + (c2 + c3);
        const float s = fmaf(-2.0f, dot, ysq[n]);
        if (s < best) {            // strict <: first index wins ties
            second = best;
            best = s;
            bestIdx = n;
        } else if (s < second) {
            second = s;
        }
    }

    s_best[wave][lane]   = best;
    s_second[wave][lane] = second;
    s_idx[wave][lane]    = bestIdx;
    __syncthreads();

    if (threadIdx.x < 64) {
        const int l = threadIdx.x;
        float gb = s_best[0][l];
        float gs = s_second[0][l];
        int   gi = s_idx[0][l];
        // Chunks are index-ordered; strict < keeps earliest chunk on ties.
#pragma unroll
        for (int c = 1; c < 4; ++c) {
            const float b  = s_best[c][l];
            const float sc = s_second[c][l];
            const int   bi = s_idx[c][l];
            if (b < gb) {
                gs = fminf(gb, sc);
                gb = b;
                gi = bi;
            } else {
                gs = fminf(gs, b);
            }
        }
        const int mm = blockIdx.x * 64 + l;
        bool ambiguous = (gs - gb <= TIE_EPS);
        if (ambiguous) {
            const int pos = atomicAdd(cnt, 1);
            if (pos < list_cap) {
                list[pos] = mm;
            } else {
                ambiguous = false;   // overflow fallback: keep fp32 winner
            }
        }
        if (!ambiguous) {
            const float* c = colors + (size_t)gi * 3;
            float* o = out + (size_t)mm * 3;
            o[0] = c[0];
            o[1] = c[1];
            o[2] = c[2];
        }
    }
}

// ---------------------------------------------------------------------------
// Kernel 3 (rescan): one WAVE per ambiguous row; lanes split the 4000 verts;
// fp64 scores reproduce the float64 numpy reference exactly. Lexicographic
// (s, idx) shuffle-reduce = first-index argmin semantics.
// ---------------------------------------------------------------------------
__global__ __launch_bounds__(256) void rescan_kernel(
    const float* __restrict__ x_all,
    const float* __restrict__ colors,
    const float* __restrict__ verts,
    const int* __restrict__ cnt,
    const int* __restrict__ list,
    int list_cap,
    float* __restrict__ out)
{
    const int wavesPerBlock = blockDim.x >> 6;
    const int wid  = blockIdx.x * wavesPerBlock + (threadIdx.x >> 6);
    const int lane = threadIdx.x & 63;
    const int nWaves = gridDim.x * wavesPerBlock;

    int c = *cnt;
    if (c > list_cap) c = list_cap;

    for (int r = wid; r < c; r += nWaves) {
        const int m = list[r];
        double bx[D_DIM];
#pragma unroll
        for (int d = 0; d < D_DIM; ++d)
            bx[d] = (double)x_all[(size_t)m * D_DIM + d];

        double best = INFINITY;
        int bi = 0x7fffffff;
        for (int n = lane; n < N_VERTS; n += 64) {
            const float* y = verts + n * D_DIM;
            double dot = 0.0, ys = 0.0;
#pragma unroll
            for (int d = 0; d < D_DIM; ++d) {
                const double yd = (double)y[d];
                dot = fma(bx[d], yd, dot);
                ys  = fma(yd, yd, ys);
            }
            const double s = ys - 2.0 * dot;
            if (s < best || (s == best && n < bi)) { best = s; bi = n; }
        }
        // Butterfly argmin reduce over 64 lanes, (s, idx) lexicographic.
#pragma unroll
        for (int off = 32; off > 0; off >>= 1) {
            const double ob = __shfl_xor(best, off, 64);
            const int    oi = __shfl_xor(bi, off, 64);
            if (ob < best || (ob == best && oi < bi)) { best = ob; bi = oi; }
        }
        if (lane == 0) {
            const float* cc = colors + (size_t)bi * 3;
            float* o = out + (size_t)m * 3;
            o[0] = cc[0];
            o[1] = cc[1];
            o[2] = cc[2];
        }
    }
}

// ---------------------------------------------------------------------------
extern "C" void kernel_launch(void* const* d_in, const int* in_sizes, int n_in,
                              void* d_out, int out_size, void* d_ws, size_t ws_size,
                              hipStream_t stream) {
    const float* cse_embedding       = (const float*)d_in[0]; // (M,16)
    const float* verts_colors        = (const float*)d_in[1]; // (N,3)
    const float* verts_cse_embedding = (const float*)d_in[2]; // (N,16)
    float* out = (float*)d_out;                               // (M,3)

    char* ws = (char*)d_ws;
    float* ysq = (float*)(ws + WS_YSQ_OFF);
    int*   cnt = (int*)(ws + WS_CNT_OFF);
    int*   list = (int*)(ws + WS_LIST_OFF);
    int list_cap = (int)((ws_size > WS_LIST_OFF)
                         ? ((ws_size - WS_LIST_OFF) / sizeof(int)) : 0);
    if (list_cap > M_ROWS) list_cap = M_ROWS;

    ysq_kernel<<<(N_VERTS + 255) / 256, 256, 0, stream>>>(
        verts_cse_embedding, ysq, cnt);

    screen_kernel<<<M_ROWS / 64, 256, 0, stream>>>(
        cse_embedding, verts_colors, verts_cse_embedding, ysq, out,
        cnt, list, list_cap);

    rescan_kernel<<<256, 256, 0, stream>>>(
        cse_embedding, verts_colors, verts_cse_embedding, cnt, list,
        list_cap, out);
}

// Round 4
// 319.041 us; speedup vs baseline: 13.2001x; 3.2449x over previous
//
#include <hip/hip_runtime.h>
#include <math.h>

// Problem: M=131072 rows, N=4000 verts (padded to 4096), D=16.
#define M_ROWS   131072
#define N_VERTS  4000
#define N_PAD    4096
#define D_DIM    16

// MFMA screen error budget: split-bf16 worst-case score error ~1.2e-2.
// TIE_EPS = 0.05 gives >4x margin; ~2% of rows rescan in fp64 (cheap).
#define TIE_EPS 0.05f

// Tiles: 16x16x32 MFMA. 256 n-tiles of 16 cols. Chunked through LDS.
#define CHUNK_T  16                  // n-tiles per LDS chunk
#define CHUNK_V  (CHUNK_T * 16)      // 256 verts per chunk
#define N_CHUNKS (N_PAD / CHUNK_V)   // 16
#define YROW_B   48                  // padded row stride (bytes) for 16 bf16
                                     // (48B -> lanes c and c+8 share banks: 2-way, free)

// d_ws layout (bytes):
//   [0       .. 196608)  Yh  : N_PAD rows x 48 B (16 bf16 of y_hi, 16 B pad)
//   [196608  .. 393216)  Yl  : N_PAD rows x 48 B (y_lo)
//   [393216  .. 409600)  Ysq : N_PAD floats (pad rows = 1e30)
//   [409600  .. 409604)  cnt
//   [409664  .. ...   )  list (ambiguous row indices)
#define WS_YH_OFF   0
#define WS_YL_OFF   196608
#define WS_YSQ_OFF  393216
#define WS_CNT_OFF  409600
#define WS_LIST_OFF 409664

typedef float f32x4 __attribute__((ext_vector_type(4)));
typedef short s16x8 __attribute__((ext_vector_type(8)));

__device__ __forceinline__ unsigned short f32_to_bf16_rne(float f) {
    unsigned int u = __float_as_uint(f);
    u = (u + 0x7fffu + ((u >> 16) & 1u)) >> 16;
    return (unsigned short)u;
}
__device__ __forceinline__ float bf16_to_f32(unsigned short h) {
    return __uint_as_float(((unsigned int)h) << 16);
}

// ---------------------------------------------------------------------------
// Kernel 1: pack Y into split-bf16 (hi/lo) rows + ysq; zero the atomic cnt.
// Pad rows (n >= 4000): y = 0, ysq = 1e30 (never wins the argmin).
// ---------------------------------------------------------------------------
__global__ void pack_y_kernel(const float* __restrict__ verts,
                              char* __restrict__ yh,
                              char* __restrict__ yl,
                              float* __restrict__ ysq,
                              int* __restrict__ cnt) {
    const int n = blockIdx.x * blockDim.x + threadIdx.x;
    if (n == 0) *cnt = 0;
    if (n >= N_PAD) return;

    unsigned short h[D_DIM], l[D_DIM];
    float ys;
    if (n < N_VERTS) {
        const float* y = verts + (size_t)n * D_DIM;
        ys = 0.f;
#pragma unroll
        for (int d = 0; d < D_DIM; ++d) {
            const float v = y[d];
            ys = fmaf(v, v, ys);
            const unsigned short hh = f32_to_bf16_rne(v);
            h[d] = hh;
            l[d] = f32_to_bf16_rne(v - bf16_to_f32(hh));
        }
    } else {
        ys = 1e30f;
#pragma unroll
        for (int d = 0; d < D_DIM; ++d) { h[d] = 0; l[d] = 0; }
    }
    ysq[n] = ys;
    s16x8* ph = (s16x8*)(yh + (size_t)n * YROW_B);
    s16x8* pl = (s16x8*)(yl + (size_t)n * YROW_B);
#pragma unroll
    for (int half = 0; half < 2; ++half) {
        s16x8 vh, vl;
#pragma unroll
        for (int j = 0; j < 8; ++j) {
            vh[j] = (short)h[half * 8 + j];
            vl[j] = (short)l[half * 8 + j];
        }
        ph[half] = vh;
        pl[half] = vl;
    }
}

// ---------------------------------------------------------------------------
// Kernel 2 (MFMA screen): block = 512 thr = 8 waves, each wave = 16 rows.
// A (per wave, built once) = [-2x as bf16 hi(16) | lo(16)], K=32.
// Per n-tile: acc init = ysq[n]; acc = A*[yh,yh] + acc; acc = A*[yl,yl] + acc
//   => acc = ysq - 2*x.(yh+yl) in fp32, error ~1e-2 worst case.
// Per-lane running (best, second, idx) over n = tile*16 + (lane&15);
// 4-step shuffle reduce across the 16 lanes of each quad at the end.
// Ambiguous rows (gap <= TIE_EPS) -> list for fp64 rescan.
// ---------------------------------------------------------------------------
__global__ __launch_bounds__(512, 8) void mfma_screen_kernel(
    const float* __restrict__ x_all,    // (M,16)
    const float* __restrict__ colors,   // (N,3)
    const char* __restrict__ yh,        // N_PAD x 48B
    const char* __restrict__ yl,        // N_PAD x 48B
    const float* __restrict__ ysqp,     // N_PAD
    float* __restrict__ out,            // (M,3)
    int* __restrict__ cnt,
    int* __restrict__ list,
    int list_cap)
{
    __shared__ __align__(16) char s_yh[CHUNK_V * YROW_B];   // 12288 B
    __shared__ __align__(16) char s_yl[CHUNK_V * YROW_B];   // 12288 B
    __shared__ float s_ysq[CHUNK_V];                        // 1024 B

    const int tid  = threadIdx.x;
    const int wave = tid >> 6;
    const int lane = tid & 63;
    const int c = lane & 15;            // n-class (B col) == m (A row)
    const int q = lane >> 4;            // quad
    const int rowBase = blockIdx.x * 128 + wave * 16;

    // --- Build A fragment: a = -2*x, split bf16. Lane needs k = q*8..q*8+7
    // of [ah(16) | al(16)]: half = q&1 selects x[0:8]/x[8:16]; q>=2 -> lo.
    const int m_a = rowBase + c;
    const float* xr = x_all + (size_t)m_a * D_DIM + (q & 1) * 8;
    const float4 xa = *(const float4*)(xr);
    const float4 xb = *(const float4*)(xr + 4);
    const float xv[8] = {xa.x, xa.y, xa.z, xa.w, xb.x, xb.y, xb.z, xb.w};
    s16x8 afrag;
    const bool lo_half = (q >= 2);
#pragma unroll
    for (int j = 0; j < 8; ++j) {
        const float a = -2.0f * xv[j];
        const unsigned short hi = f32_to_bf16_rne(a);
        unsigned short r = hi;
        if (lo_half) r = f32_to_bf16_rne(a - bf16_to_f32(hi));
        afrag[j] = (short)r;
    }

    float best[4]   = {INFINITY, INFINITY, INFINITY, INFINITY};
    float second[4] = {INFINITY, INFINITY, INFINITY, INFINITY};
    int   idx[4]    = {0, 0, 0, 0};

    const int off0 = c * YROW_B + (q & 1) * 16;   // lane's B-frag byte offset

    for (int ch = 0; ch < N_CHUNKS; ++ch) {
        __syncthreads();
        // Stage chunk: Yh/Yl rows [ch*256, ch*256+256) + ysq. int4 copies.
        {
            const int4* gh = (const int4*)(yh + (size_t)ch * CHUNK_V * YROW_B);
            const int4* gl = (const int4*)(yl + (size_t)ch * CHUNK_V * YROW_B);
            int4* sh = (int4*)s_yh;
            int4* sl = (int4*)s_yl;
            const int n16 = CHUNK_V * YROW_B / 16;   // 768
            for (int i = tid; i < n16; i += 512) {
                sh[i] = gh[i];
                sl[i] = gl[i];
            }
            const int4* gq = (const int4*)(ysqp + (size_t)ch * CHUNK_V);
            int4* sq = (int4*)s_ysq;
            if (tid < CHUNK_V / 4) sq[tid] = gq[tid];
        }
        __syncthreads();

        const int baseN = ch * CHUNK_V;
#pragma unroll 4
        for (int t = 0; t < CHUNK_T; ++t) {
            const s16x8 byh = *(const s16x8*)(s_yh + t * 16 * YROW_B + off0);
            const s16x8 byl = *(const s16x8*)(s_yl + t * 16 * YROW_B + off0);
            const float ys = s_ysq[t * 16 + c];
            f32x4 acc = {ys, ys, ys, ys};
            acc = __builtin_amdgcn_mfma_f32_16x16x32_bf16(afrag, byh, acc, 0, 0, 0);
            acc = __builtin_amdgcn_mfma_f32_16x16x32_bf16(afrag, byl, acc, 0, 0, 0);
            const int n = baseN + t * 16 + c;
#pragma unroll
            for (int r = 0; r < 4; ++r) {
                const float s  = acc[r];
                const float ob = best[r];
                second[r] = fminf(second[r], fmaxf(ob, s));
                best[r]   = fminf(ob, s);
                idx[r]    = (s < ob) ? n : idx[r];
            }
        }
    }

    // --- Cross-lane merge among the 16 lanes of each quad (xor 1,2,4,8).
#pragma unroll
    for (int off = 1; off < 16; off <<= 1) {
#pragma unroll
        for (int r = 0; r < 4; ++r) {
            const float ob = __shfl_xor(best[r], off, 64);
            const float os = __shfl_xor(second[r], off, 64);
            const int   oi = __shfl_xor(idx[r], off, 64);
            const float mx = fmaxf(best[r], ob);
            second[r] = fminf(fminf(second[r], os), mx);
            int ni;
            if (ob < best[r]) ni = oi;
            else if (ob == best[r]) ni = min(idx[r], oi);
            else ni = idx[r];
            best[r] = fminf(best[r], ob);
            idx[r] = ni;
        }
    }

    // --- Writers: lane c==0 of each quad finalizes rows q*4 + r.
    if (c == 0) {
#pragma unroll
        for (int r = 0; r < 4; ++r) {
            const int m = rowBase + q * 4 + r;
            bool amb = (second[r] - best[r] <= TIE_EPS);
            if (amb) {
                const int pos = atomicAdd(cnt, 1);
                if (pos < list_cap) list[pos] = m;
                else amb = false;   // overflow: keep screened winner
            }
            if (!amb) {
                const float* cc = colors + (size_t)idx[r] * 3;
                float* o = out + (size_t)m * 3;
                o[0] = cc[0];
                o[1] = cc[1];
                o[2] = cc[2];
            }
        }
    }
}

// ---------------------------------------------------------------------------
// Kernel 3 (rescan): one wave per ambiguous row, fp64 exact, lanes split
// verts, lexicographic (s, idx) butterfly = np.argmin first-index semantics.
// ---------------------------------------------------------------------------
__global__ __launch_bounds__(256) void rescan_kernel(
    const float* __restrict__ x_all,
    const float* __restrict__ colors,
    const float* __restrict__ verts,
    const int* __restrict__ cnt,
    const int* __restrict__ list,
    int list_cap,
    float* __restrict__ out)
{
    const int wavesPerBlock = blockDim.x >> 6;
    const int wid  = blockIdx.x * wavesPerBlock + (threadIdx.x >> 6);
    const int lane = threadIdx.x & 63;
    const int nWaves = gridDim.x * wavesPerBlock;

    int ccount = *cnt;
    if (ccount > list_cap) ccount = list_cap;

    for (int rr = wid; rr < ccount; rr += nWaves) {
        const int m = list[rr];
        double bx[D_DIM];
#pragma unroll
        for (int d = 0; d < D_DIM; ++d)
            bx[d] = (double)x_all[(size_t)m * D_DIM + d];

        double best = INFINITY;
        int bi = 0x7fffffff;
        for (int n = lane; n < N_VERTS; n += 64) {
            const float* y = verts + (size_t)n * D_DIM;
            double dot = 0.0, ys = 0.0;
#pragma unroll
            for (int d = 0; d < D_DIM; ++d) {
                const double yd = (double)y[d];
                dot = fma(bx[d], yd, dot);
                ys  = fma(yd, yd, ys);
            }
            const double s = ys - 2.0 * dot;
            if (s < best || (s == best && n < bi)) { best = s; bi = n; }
        }
#pragma unroll
        for (int off = 32; off > 0; off >>= 1) {
            const double ob = __shfl_xor(best, off, 64);
            const int    oi = __shfl_xor(bi, off, 64);
            if (ob < best || (ob == best && oi < bi)) { best = ob; bi = oi; }
        }
        if (lane == 0) {
            const float* cc = colors + (size_t)bi * 3;
            float* o = out + (size_t)m * 3;
            o[0] = cc[0];
            o[1] = cc[1];
            o[2] = cc[2];
        }
    }
}

// ---------------------------------------------------------------------------
extern "C" void kernel_launch(void* const* d_in, const int* in_sizes, int n_in,
                              void* d_out, int out_size, void* d_ws, size_t ws_size,
                              hipStream_t stream) {
    const float* cse_embedding       = (const float*)d_in[0]; // (M,16)
    const float* verts_colors        = (const float*)d_in[1]; // (N,3)
    const float* verts_cse_embedding = (const float*)d_in[2]; // (N,16)
    float* out = (float*)d_out;                               // (M,3)

    char* ws = (char*)d_ws;
    char*  yh   = ws + WS_YH_OFF;
    char*  yl   = ws + WS_YL_OFF;
    float* ysq  = (float*)(ws + WS_YSQ_OFF);
    int*   cnt  = (int*)(ws + WS_CNT_OFF);
    int*   list = (int*)(ws + WS_LIST_OFF);
    int list_cap = (int)((ws_size > WS_LIST_OFF)
                         ? ((ws_size - WS_LIST_OFF) / sizeof(int)) : 0);
    if (list_cap > M_ROWS) list_cap = M_ROWS;

    pack_y_kernel<<<N_PAD / 256, 256, 0, stream>>>(
        verts_cse_embedding, yh, yl, ysq, cnt);

    mfma_screen_kernel<<<M_ROWS / 128, 512, 0, stream>>>(
        cse_embedding, verts_colors, yh, yl, ysq, out, cnt, list, list_cap);

    rescan_kernel<<<256, 256, 0, stream>>>(
        cse_embedding, verts_colors, verts_cse_embedding, cnt, list,
        list_cap, out);
}

// Round 5
// 201.517 us; speedup vs baseline: 20.8983x; 1.5832x over previous
//
#include <hip/hip_runtime.h>
#include <math.h>
#include <stdint.h>

// Problem: M=131072 rows, N=4000 verts (padded to 4096), D=16.
#define M_ROWS   131072
#define N_VERTS  4000
#define N_PAD    4096
#define D_DIM    16
#define N_TILES  (N_PAD / 16)        // 256 n-tiles of 16 verts
#define CHUNK_T  16                  // tiles per LDS chunk
#define CHUNK_B  (CHUNK_T * 1024)    // 16384 B per chunk (64 lanes x 16 B x 16 tiles)
#define N_CHUNKS (N_TILES / CHUNK_T) // 16

// Scores are biased +128 so they are provably positive (score >= -||x||^2 and
// ||x||^2 < 128 for chi^2_16 data at astronomical confidence) -> positive-float
// bit pattern is monotone as u32 -> min_u32 does argmin via packed keys.
#define SCORE_BIAS 128.0f
// key = (score_bits & ~0xFF) | tile. Error budget: 8-bit mantissa truncation
// <= 7.8e-3, split-bf16 arithmetic <= ~1e-3 (Cauchy-Schwarz bound 6.9e-4 +
// fp32 accum 2e-4). TIE_EPS = 0.025 >= 2x total with margin.
#define TIE_EPS 0.025f

// d_ws layout (bytes):
//   [0      .. 262144)  yfrag : N_TILES x 1024 B, fragment-ordered split-bf16
//   [262144 .. 278528)  ysq   : N_PAD floats (score bias baked in; pads 1e30)
//   [278528 .. 278532)  cnt
//   [278592 .. ...   )  list  : ambiguous row indices
#define WS_YFRAG_OFF 0
#define WS_YSQ_OFF   262144
#define WS_CNT_OFF   278528
#define WS_LIST_OFF  278592

typedef float f32x4 __attribute__((ext_vector_type(4)));
typedef short s16x8 __attribute__((ext_vector_type(8)));

__device__ __forceinline__ unsigned short f32_to_bf16_rne(float f) {
    unsigned int u = __float_as_uint(f);
    u = (u + 0x7fffu + ((u >> 16) & 1u)) >> 16;
    return (unsigned short)u;
}
__device__ __forceinline__ float bf16_to_f32(unsigned short h) {
    return __uint_as_float(((unsigned int)h) << 16);
}
__device__ __forceinline__ uint32_t umin32(uint32_t a, uint32_t b) { return a < b ? a : b; }
__device__ __forceinline__ uint32_t umax32(uint32_t a, uint32_t b) { return a > b ? a : b; }

// ---------------------------------------------------------------------------
// Kernel 1: pack Y into fragment-ordered split-bf16 + biased ysq.
// Fragment layout (verified via R4 absmax=0): B[n = lane&15][k = (lane>>4)*8+j]
// with B = [yh(k 0..15) | yl(k 16..31)]. Byte offset = tile*1024 + lane*16.
// One thread per (tile, lane) = 16384 threads.
// ---------------------------------------------------------------------------
__global__ void pack_y_kernel(const float* __restrict__ verts,
                              char* __restrict__ yfrag,
                              float* __restrict__ ysq,
                              int* __restrict__ cnt) {
    const int tid = blockIdx.x * blockDim.x + threadIdx.x;   // 0..16383
    if (tid == 0) *cnt = 0;

    {
        const int T = tid >> 6;
        const int l = tid & 63;
        const int q = l >> 4;
        const int c = l & 15;
        const int n = T * 16 + c;
        float v[8];
        if (n < N_VERTS) {
            const float* y = verts + (size_t)n * D_DIM + (q & 1) * 8;
#pragma unroll
            for (int j = 0; j < 8; ++j) v[j] = y[j];
        } else {
#pragma unroll
            for (int j = 0; j < 8; ++j) v[j] = 0.f;
        }
        s16x8 f;
        const bool lo = (q >= 2);
#pragma unroll
        for (int j = 0; j < 8; ++j) {
            const unsigned short hh = f32_to_bf16_rne(v[j]);
            unsigned short r = hh;
            if (lo) r = f32_to_bf16_rne(v[j] - bf16_to_f32(hh));
            f[j] = (short)r;
        }
        *(s16x8*)(yfrag + (size_t)tid * 16) = f;
    }

    if (tid < N_PAD) {
        float ys;
        if (tid < N_VERTS) {
            ys = SCORE_BIAS;
            const float* y = verts + (size_t)tid * D_DIM;
#pragma unroll
            for (int d = 0; d < D_DIM; ++d) ys = fmaf(y[d], y[d], ys);
        } else {
            ys = 1e30f;   // pad cols never win
        }
        ysq[tid] = ys;
    }
}

// ---------------------------------------------------------------------------
// Kernel 2 (MFMA screen): 512 thr = 8 waves, wave = 16 rows over all 4096 n.
// A1=[ah|ah], A2=[al|al] (a = -2x split bf16); B=[yh|yl] single b128/tile.
// acc init = ysq[n]+bias; two chained MFMAs give score+bias in fp32.
// Key = (bits & ~0xFF) | tile -> min_u32 tracks best+argmin, max/min second.
// Double-buffered LDS chunks, ONE barrier per chunk (reg-prefetch).
// ---------------------------------------------------------------------------
__global__ __launch_bounds__(512, 6) void mfma_screen_kernel(
    const float* __restrict__ x_all,    // (M,16)
    const float* __restrict__ colors,   // (N,3)
    const char* __restrict__ yfrag,     // N_TILES x 1024 B
    const float* __restrict__ ysqg,     // N_PAD (biased)
    float* __restrict__ out,            // (M,3)
    int* __restrict__ cnt,
    int* __restrict__ list,
    int list_cap)
{
    __shared__ __align__(16) char  s_buf[2 * CHUNK_B];   // 32 KB (reused for reduce)
    __shared__ __align__(16) float s_ysq[N_PAD];         // 16 KB

    const int tid  = threadIdx.x;
    const int wave = tid >> 6;
    const int lane = tid & 63;
    const int q = lane >> 4;
    const int c = lane & 15;
    const int rowBase = blockIdx.x * 128 + wave * 16;

    // --- A fragments (built once). Lane supplies A[m=c][k=q*8+j].
    // A1[k] = ah[k mod 16], A2[k] = al[k mod 16] -> half select = q&1.
    const float* xr = x_all + (size_t)(rowBase + c) * D_DIM + (q & 1) * 8;
    const float4 xa = *(const float4*)xr;
    const float4 xb = *(const float4*)(xr + 4);
    const float xv[8] = {xa.x, xa.y, xa.z, xa.w, xb.x, xb.y, xb.z, xb.w};
    s16x8 a1, a2;
#pragma unroll
    for (int j = 0; j < 8; ++j) {
        const float a = -2.0f * xv[j];
        const unsigned short hh = f32_to_bf16_rne(a);
        a1[j] = (short)hh;
        a2[j] = (short)f32_to_bf16_rne(a - bf16_to_f32(hh));
    }

    // --- Stage ysq once (1024 int4, 2 per thread).
    {
        const int4* g = (const int4*)ysqg;
        int4* s = (int4*)s_ysq;
        s[tid] = g[tid];
        s[tid + 512] = g[tid + 512];
    }
    // --- Prologue: chunk 0 -> buf0 (stride-16B per thread: conflict-free).
    const int4* gy = (const int4*)yfrag;
    int4 ra = gy[tid];
    int4 rb = gy[512 + tid];
    {
        int4* s = (int4*)s_buf;
        s[tid] = ra;
        s[512 + tid] = rb;
    }

    uint32_t best[4]   = {0xFFFFFFFFu, 0xFFFFFFFFu, 0xFFFFFFFFu, 0xFFFFFFFFu};
    uint32_t second[4] = {0xFFFFFFFFu, 0xFFFFFFFFu, 0xFFFFFFFFu, 0xFFFFFFFFu};

    for (int ch = 0; ch < N_CHUNKS; ++ch) {
        // Prefetch next chunk into regs BEFORE the barrier (latency overlap).
        if (ch + 1 < N_CHUNKS) {
            ra = gy[(ch + 1) * 1024 + tid];
            rb = gy[(ch + 1) * 1024 + 512 + tid];
        }
        __syncthreads();   // buf[ch&1] writes (prev iter / prologue) visible

        const char*  bb    = s_buf + (ch & 1) * CHUNK_B + lane * 16;
        const float* ysrow = s_ysq + ch * CHUNK_T * 16 + c;
#pragma unroll
        for (int t = 0; t < CHUNK_T; ++t) {
            const s16x8 bf = *(const s16x8*)(bb + t * 1024);  // lane*16: conflict-free
            const float ys = ysrow[t * 16];                    // broadcast: free
            f32x4 acc = {ys, ys, ys, ys};
            acc = __builtin_amdgcn_mfma_f32_16x16x32_bf16(a1, bf, acc, 0, 0, 0);
            acc = __builtin_amdgcn_mfma_f32_16x16x32_bf16(a2, bf, acc, 0, 0, 0);
            const uint32_t tcur = (uint32_t)(ch * CHUNK_T + t);
#pragma unroll
            for (int r = 0; r < 4; ++r) {
                const uint32_t kb = (__float_as_uint(acc[r]) & 0xFFFFFF00u) | tcur;
                const uint32_t ob = best[r];
                second[r] = umin32(second[r], umax32(ob, kb));
                best[r]   = umin32(ob, kb);
            }
        }
        // Write next chunk to the OTHER buffer (safe: its last readers were
        // fenced by this iteration's top barrier).
        if (ch + 1 < N_CHUNKS) {
            int4* s = (int4*)(s_buf + ((ch + 1) & 1) * CHUNK_B);
            s[tid] = ra;
            s[512 + tid] = rb;
        }
    }

    // --- Reduce across the 16 c-subclasses. Reuse s_buf:
    //   keys:    [wave*256 + row*16 + c]           (8 KB)
    //   seconds: 8192 B offset, same indexing      (8 KB)
    __syncthreads();
    uint32_t* s_red  = (uint32_t*)s_buf;
    uint32_t* s_red2 = (uint32_t*)(s_buf + 8192);
#pragma unroll
    for (int r = 0; r < 4; ++r) {
        const int row = q * 4 + r;    // C/D: row = (lane>>4)*4 + reg
        s_red [wave * 256 + row * 16 + c] = best[r];
        s_red2[wave * 256 + row * 16 + c] = second[r];
    }
    __syncthreads();

    if (lane < 16) {
        const int row = lane;
        uint32_t b1 = 0xFFFFFFFFu, b2 = 0xFFFFFFFFu, smin = 0xFFFFFFFFu;
        int cwin = 0;
#pragma unroll
        for (int cc = 0; cc < 16; ++cc) {
            const uint32_t k  = s_red [wave * 256 + row * 16 + cc];
            const uint32_t s2 = s_red2[wave * 256 + row * 16 + cc];
            smin = umin32(smin, s2);
            cwin = (k < b1) ? cc : cwin;        // strict <: earliest c on equal keys
            b2 = umin32(b2, umax32(b1, k));     // 2nd-min of bests
            b1 = umin32(b1, k);
        }
        const uint32_t secondAll = umin32(smin, b2);
        const float s1 = __uint_as_float(b1 & 0xFFFFFF00u);
        const float s2 = __uint_as_float(secondAll & 0xFFFFFF00u);
        const int n = (int)(b1 & 0xFFu) * 16 + cwin;
        const int m = rowBase + row;

        bool amb = (s2 - s1 <= TIE_EPS);
        if (amb) {
            const int pos = atomicAdd(cnt, 1);
            if (pos < list_cap) list[pos] = m;
            else amb = false;                   // overflow: keep screened winner
        }
        if (!amb) {
            const float* cc2 = colors + (size_t)n * 3;
            float* o = out + (size_t)m * 3;
            o[0] = cc2[0];
            o[1] = cc2[1];
            o[2] = cc2[2];
        }
    }
}

// ---------------------------------------------------------------------------
// Kernel 3 (rescan): one wave per ambiguous row, fp64 exact (= f64 numpy ref),
// 8192 waves so latency is hidden by TLP; unroll-2 for ILP within a wave.
// ---------------------------------------------------------------------------
__global__ __launch_bounds__(256) void rescan_kernel(
    const float* __restrict__ x_all,
    const float* __restrict__ colors,
    const float* __restrict__ verts,
    const int* __restrict__ cnt,
    const int* __restrict__ list,
    int list_cap,
    float* __restrict__ out)
{
    const int wavesPerBlock = blockDim.x >> 6;
    const int wid  = blockIdx.x * wavesPerBlock + (threadIdx.x >> 6);
    const int lane = threadIdx.x & 63;
    const int nWaves = gridDim.x * wavesPerBlock;

    int ccount = *cnt;
    if (ccount > list_cap) ccount = list_cap;

    for (int rr = wid; rr < ccount; rr += nWaves) {
        const int m = list[rr];
        double bx[D_DIM];
#pragma unroll
        for (int d = 0; d < D_DIM; ++d)
            bx[d] = (double)x_all[(size_t)m * D_DIM + d];

        double best = INFINITY;
        int bi = 0x7fffffff;
#pragma unroll 2
        for (int n = lane; n < N_VERTS; n += 64) {
            const float* y = verts + (size_t)n * D_DIM;
            double dot = 0.0, ys = 0.0;
#pragma unroll
            for (int d = 0; d < D_DIM; ++d) {
                const double yd = (double)y[d];
                dot = fma(bx[d], yd, dot);
                ys  = fma(yd, yd, ys);
            }
            const double s = ys - 2.0 * dot;
            if (s < best || (s == best && n < bi)) { best = s; bi = n; }
        }
#pragma unroll
        for (int off = 32; off > 0; off >>= 1) {
            const double ob = __shfl_xor(best, off, 64);
            const int    oi = __shfl_xor(bi, off, 64);
            if (ob < best || (ob == best && oi < bi)) { best = ob; bi = oi; }
        }
        if (lane == 0) {
            const float* cc = colors + (size_t)bi * 3;
            float* o = out + (size_t)m * 3;
            o[0] = cc[0];
            o[1] = cc[1];
            o[2] = cc[2];
        }
    }
}

// ---------------------------------------------------------------------------
extern "C" void kernel_launch(void* const* d_in, const int* in_sizes, int n_in,
                              void* d_out, int out_size, void* d_ws, size_t ws_size,
                              hipStream_t stream) {
    const float* cse_embedding       = (const float*)d_in[0]; // (M,16)
    const float* verts_colors        = (const float*)d_in[1]; // (N,3)
    const float* verts_cse_embedding = (const float*)d_in[2]; // (N,16)
    float* out = (float*)d_out;                               // (M,3)

    char* ws = (char*)d_ws;
    char*  yfrag = ws + WS_YFRAG_OFF;
    float* ysq   = (float*)(ws + WS_YSQ_OFF);
    int*   cnt   = (int*)(ws + WS_CNT_OFF);
    int*   list  = (int*)(ws + WS_LIST_OFF);
    int list_cap = (int)((ws_size > WS_LIST_OFF)
                         ? ((ws_size - WS_LIST_OFF) / sizeof(int)) : 0);
    if (list_cap > M_ROWS) list_cap = M_ROWS;

    pack_y_kernel<<<(N_TILES * 64) / 256, 256, 0, stream>>>(
        verts_cse_embedding, yfrag, ysq, cnt);

    mfma_screen_kernel<<<M_ROWS / 128, 512, 0, stream>>>(
        cse_embedding, verts_colors, yfrag, ysq, out, cnt, list, list_cap);

    rescan_kernel<<<2048, 256, 0, stream>>>(
        cse_embedding, verts_colors, verts_cse_embedding, cnt, list,
        list_cap, out);
}